// Round 6
// baseline (717.163 us; speedup 1.0000x reference)
//
#include <hip/hip_runtime.h>
#include <hip/hip_bf16.h>
#include <hip/hip_fp16.h>

// CircuitGNN: 3-layer GCN (N=500k, E=1M, H=64) + mean pool + tanh FC head.
// v6: layer_kernel latency fixes:
//     - 1 group (16 nodes) per wave, grid ~7813 blocks (v5's LB=768 left
//       occupancy dispatch-limited at 30%).
//     - group CSR span prefetched with ONE global load into 2 lane-vectors
//       (segments are contiguous; span<=128 fast path, serial fallback),
//       16 self-rows hoisted (independent loads), gather loop i-outer/m-inner
//       so up to 16 row loads are in flight per wait. All control flow
//       wave-uniform (off/deg in SGPRs via readlane).
//     - layer1 = agg1+mm1 fused (wave-per-node, xs float4 broadcasts).
// v5 core kept: per-wave LDS A-tile + 8x mfma_f32_16x16x32_f16 vs
//     register-stationary W frags; h stored fp16 prescaled by dinv.
// History: v2 swizzled-LDS full-unroll spilled (VGPR 256) -- avoid.
//          v3/v4 readlane matmul: VALU-issue-bound (128 insts/node).
// Storage fp16; compute fp32 (MFMA f16-in/f32-acc).

#define ALIGN256(x) (((x) + 255) & ~(size_t)255)

typedef _Float16 half8 __attribute__((ext_vector_type(8)));
typedef float f32x4 __attribute__((ext_vector_type(4)));

__device__ __forceinline__ float rl(float v, int lane) {
    return __builtin_bit_cast(float, __builtin_amdgcn_readlane(__builtin_bit_cast(int, v), lane));
}

__global__ __launch_bounds__(256) void deg_kernel(const int* __restrict__ dst, int* __restrict__ cnt, int E) {
    int e = blockIdx.x * 256 + threadIdx.x;
    if (e < E) atomicAdd(&cnt[dst[e]], 1);
}

// dinv + prescaled xs (xs = dinv * x, padded to float4)
__global__ __launch_bounds__(256) void dinvx_kernel(const int* __restrict__ cnt, const float* __restrict__ x,
                                                    float* __restrict__ dinv, float4* __restrict__ xs, int N) {
    int i = blockIdx.x * 256 + threadIdx.x;
    if (i < N) {
        float d = rsqrtf((float)(cnt[i] + 1));   // +1 = self loop
        dinv[i] = d;
        xs[i] = make_float4(d * x[(size_t)i * 3 + 0], d * x[(size_t)i * 3 + 1],
                            d * x[(size_t)i * 3 + 2], 0.f);
    }
}

// ---- 2-level exclusive scan over cnt[N] ----
__global__ __launch_bounds__(256) void scan1_kernel(const int* __restrict__ cnt, int* __restrict__ bsum, int N) {
    __shared__ int s[256];
    int t = threadIdx.x, b = blockIdx.x;
    int i0 = b * 1024 + t * 4;
    int v = 0;
    if (i0 + 3 < N) { int4 q = *(const int4*)&cnt[i0]; v = q.x + q.y + q.z + q.w; }
    else { for (int k = 0; k < 4; ++k) if (i0 + k < N) v += cnt[i0 + k]; }
    s[t] = v; __syncthreads();
    for (int o = 128; o > 0; o >>= 1) { if (t < o) s[t] += s[t + o]; __syncthreads(); }
    if (t == 0) bsum[b] = s[0];
}

__global__ __launch_bounds__(512) void scan2_kernel(const int* __restrict__ bsum, int* __restrict__ bbase, int nb) {
    __shared__ int s[512];
    int t = threadIdx.x;
    int v = (t < nb) ? bsum[t] : 0;
    s[t] = v; __syncthreads();
    for (int off = 1; off < 512; off <<= 1) {
        int u = 0; if (t >= off) u = s[t - off];
        __syncthreads(); s[t] += u; __syncthreads();
    }
    if (t < nb) bbase[t] = s[t] - v;   // exclusive
}

// writes od[j] = (offset, deg) and cur[j] = offset
__global__ __launch_bounds__(256) void scan3_kernel(const int* __restrict__ cnt, const int* __restrict__ bbase,
                                                    int2* __restrict__ od, int* __restrict__ cur, int N) {
    __shared__ int s[256];
    int t = threadIdx.x, b = blockIdx.x;
    int i0 = b * 1024 + t * 4;
    int v0 = 0, v1 = 0, v2 = 0, v3 = 0;
    if (i0 + 3 < N) { int4 q = *(const int4*)&cnt[i0]; v0 = q.x; v1 = q.y; v2 = q.z; v3 = q.w; }
    else {
        if (i0 < N) v0 = cnt[i0];
        if (i0 + 1 < N) v1 = cnt[i0 + 1];
        if (i0 + 2 < N) v2 = cnt[i0 + 2];
        if (i0 + 3 < N) v3 = cnt[i0 + 3];
    }
    int ts = v0 + v1 + v2 + v3;
    s[t] = ts; __syncthreads();
    for (int off = 1; off < 256; off <<= 1) {
        int u = 0; if (t >= off) u = s[t - off];
        __syncthreads(); s[t] += u; __syncthreads();
    }
    int ex = s[t] - ts + bbase[b];
    int o0 = ex, o1 = ex + v0, o2 = o1 + v1, o3 = o2 + v2;
    if (i0     < N) { od[i0]     = make_int2(o0, v0); cur[i0]     = o0; }
    if (i0 + 1 < N) { od[i0 + 1] = make_int2(o1, v1); cur[i0 + 1] = o1; }
    if (i0 + 2 < N) { od[i0 + 2] = make_int2(o2, v2); cur[i0 + 2] = o2; }
    if (i0 + 3 < N) { od[i0 + 3] = make_int2(o3, v3); cur[i0 + 3] = o3; }
}

__global__ __launch_bounds__(256) void fill_kernel(const int* __restrict__ ei, int* __restrict__ cur,
                                                   int* __restrict__ csr, int E) {
    int e = blockIdx.x * 256 + threadIdx.x;
    if (e < E) {
        int s = ei[e], d = ei[E + e];
        int p = atomicAdd(&cur[d], 1);
        csr[p] = s;
    }
}

// ---- layer 1 fused: wave per node; gather xs (float4 broadcast) + 3->64
//      matmul per lane; writes prescaled fp16 h1. ----
__global__ __launch_bounds__(256) void layer1_kernel(const float4* __restrict__ xs, const float* __restrict__ dinv,
                                                     const int2* __restrict__ od, const int* __restrict__ csr,
                                                     const float* __restrict__ W1, const float* __restrict__ b1,
                                                     __half* __restrict__ hout, int N) {
    const int l = threadIdx.x & 63;
    const int wave = blockIdx.x * 4 + (threadIdx.x >> 6);
    const int stride = gridDim.x * 4;
    const float w0 = W1[l], w1 = W1[64 + l], w2 = W1[128 + l], bl = b1[l];
    for (int j = wave; j < N; j += stride) {
        int2 o = od[j];
        float dj = dinv[j];
        float4 s = xs[j];
        const int* cp = csr + o.x;
        for (int i = 0; i < o.y; ++i) {
            float4 q = xs[cp[i]];
            s.x += q.x; s.y += q.y; s.z += q.z;
        }
        float v = fmaf(dj * s.x, w0, fmaf(dj * s.y, w1, fmaf(dj * s.z, w2, bl)));
        hout[(size_t)j * 64 + l] = __float2half(dj * fmaxf(v, 0.f));
    }
}

// ---- fused GCN layer v6: wave = 16 nodes (1 group/wave).
//      Phase A: group CSR span prefetch (1 load) + hoisted self rows +
//               i-outer/m-inner gather (<=16 loads in flight). LDS A-tile.
//      Phase B: 8x mfma_f32_16x16x32_f16 vs register-stationary W frags.
//      POOL=1 accumulates mean-pool numerator in registers. ----
template <int POOL>
__global__ __launch_bounds__(256) void layer_kernel(const __half* __restrict__ hin, const float* __restrict__ dinv,
                                                    const int2* __restrict__ od, const int* __restrict__ csr,
                                                    const float* __restrict__ W, const float* __restrict__ bias,
                                                    __half* __restrict__ hout, float* __restrict__ pool, int N) {
    const int t = threadIdx.x;
    const int l = t & 63;
    const int w = t >> 6;
    const int l15 = l & 15, q = l >> 4;

    __shared__ _Float16 aS[4][16 * 136 + 8];   // per-wave slice, row stride 136 (272 B)
    __shared__ float red[256];
    _Float16* as = aS[w];

    // B fragments of W (fp32 global -> f16 regs): lane holds
    // B[k = kt*32 + q*8 + j][col = ct*16 + l15], j=0..7. One-time, L2-hot.
    half8 bfr[4][2];
    #pragma unroll
    for (int ct = 0; ct < 4; ++ct)
        #pragma unroll
        for (int kt = 0; kt < 2; ++kt) {
            half8 b;
            #pragma unroll
            for (int j = 0; j < 8; ++j)
                b[j] = (_Float16)W[(kt * 32 + q * 8 + j) * 64 + ct * 16 + l15];
            bfr[ct][kt] = b;
        }
    float bb[4];
    #pragma unroll
    for (int ct = 0; ct < 4; ++ct) bb[ct] = bias[ct * 16 + l15];

    float ps0 = 0.f, ps1 = 0.f, ps2 = 0.f, ps3 = 0.f;

    const int ngroups = (N + 15) >> 4;
    const int gstride = gridDim.x * 4;
    for (int g = blockIdx.x * 4 + w; g < ngroups; g += gstride) {
        const int j0 = g << 4;
        // od/dinv for the group's 16 nodes (lanes 0..15, coalesced)
        float djv = 0.f; int oxv = 0, oyv = 0;
        if (l < 16 && j0 + l < N) {
            int2 o = od[j0 + l];
            oxv = o.x; oyv = o.y;
            djv = dinv[j0 + l];
        }
        // hoist offsets/degrees to SGPRs
        int offr[16], dg[16];
        const int mlast = min(15, N - 1 - j0);
        const int base = __builtin_amdgcn_readlane(oxv, 0);
        #pragma unroll
        for (int m = 0; m < 16; ++m) {
            offr[m] = __builtin_amdgcn_readlane(oxv, m) - base;
            dg[m]   = __builtin_amdgcn_readlane(oyv, m);
        }
        const int span = offr[mlast] + dg[mlast];

        // prefetch whole group's neighbor indices (contiguous in CSR)
        int nb0 = 0, nb1 = 0;
        if (l < span)      nb0 = csr[base + l];
        if (64 + l < span) nb1 = csr[base + 64 + l];

        // hoisted self rows (independent loads, one wait)
        float acc[16];
        #pragma unroll
        for (int m = 0; m < 16; ++m) {
            int j = j0 + m;
            acc[m] = (j < N) ? __half2float(hin[(size_t)j * 64 + l]) : 0.f;
        }

        if (span <= 128) {
            int dmax = 0;
            #pragma unroll
            for (int m = 0; m < 16; ++m) dmax = max(dmax, dg[m]);
            for (int i = 0; i < dmax; ++i) {
                #pragma unroll
                for (int m = 0; m < 16; ++m) {
                    if (i < dg[m]) {                       // wave-uniform branch
                        int idx = offr[m] + i;
                        int s = (idx < 64) ? __builtin_amdgcn_readlane(nb0, idx)
                                           : __builtin_amdgcn_readlane(nb1, idx - 64);
                        acc[m] += __half2float(hin[(size_t)s * 64 + l]);
                    }
                }
            }
        } else {
            // rare fallback: per-node serial gathers
            #pragma unroll 1
            for (int m = 0; m < 16; ++m) {
                const int* cp = csr + base + offr[m];
                for (int i = 0; i < dg[m]; ++i)
                    acc[m] += __half2float(hin[(size_t)cp[i] * 64 + l]);
            }
        }

        // scale + stage to LDS (A-frag layout)
        #pragma unroll
        for (int m = 0; m < 16; ++m)
            as[m * 136 + l] = (_Float16)(rl(djv, m) * acc[m]);
        __asm__ volatile("s_waitcnt lgkmcnt(0)" ::: "memory");

        // Phase B: A-frags (A[m=l15][k=q*8+j] per ktile) + 8 MFMA
        half8 af0 = *(const half8*)&as[l15 * 136 + q * 8];
        half8 af1 = *(const half8*)&as[l15 * 136 + 32 + q * 8];
        f32x4 c0 = {0.f, 0.f, 0.f, 0.f}, c1 = c0, c2 = c0, c3 = c0;
        c0 = __builtin_amdgcn_mfma_f32_16x16x32_f16(af0, bfr[0][0], c0, 0, 0, 0);
        c1 = __builtin_amdgcn_mfma_f32_16x16x32_f16(af0, bfr[1][0], c1, 0, 0, 0);
        c2 = __builtin_amdgcn_mfma_f32_16x16x32_f16(af0, bfr[2][0], c2, 0, 0, 0);
        c3 = __builtin_amdgcn_mfma_f32_16x16x32_f16(af0, bfr[3][0], c3, 0, 0, 0);
        c0 = __builtin_amdgcn_mfma_f32_16x16x32_f16(af1, bfr[0][1], c0, 0, 0, 0);
        c1 = __builtin_amdgcn_mfma_f32_16x16x32_f16(af1, bfr[1][1], c1, 0, 0, 0);
        c2 = __builtin_amdgcn_mfma_f32_16x16x32_f16(af1, bfr[2][1], c2, 0, 0, 0);
        c3 = __builtin_amdgcn_mfma_f32_16x16x32_f16(af1, bfr[3][1], c3, 0, 0, 0);

        // Epilogue: C[row = q*4+r][col = ct*16+l15]
        if (POOL) {
            #pragma unroll
            for (int r = 0; r < 4; ++r) {
                int gj = j0 + q * 4 + r;
                if (gj < N) {
                    ps0 += fmaxf(c0[r] + bb[0], 0.f);
                    ps1 += fmaxf(c1[r] + bb[1], 0.f);
                    ps2 += fmaxf(c2[r] + bb[2], 0.f);
                    ps3 += fmaxf(c3[r] + bb[3], 0.f);
                }
            }
        } else {
            #pragma unroll
            for (int r = 0; r < 4; ++r) {
                int row = q * 4 + r;
                int gj = j0 + row;
                float djr = __shfl(djv, row, 64);
                if (gj < N) {
                    size_t bse = (size_t)gj * 64 + l15;
                    hout[bse]      = __float2half(djr * fmaxf(c0[r] + bb[0], 0.f));
                    hout[bse + 16] = __float2half(djr * fmaxf(c1[r] + bb[1], 0.f));
                    hout[bse + 32] = __float2half(djr * fmaxf(c2[r] + bb[2], 0.f));
                    hout[bse + 48] = __float2half(djr * fmaxf(c3[r] + bb[3], 0.f));
                }
            }
        }
    }

    if (POOL) {
        ps0 += __shfl_xor(ps0, 16, 64); ps0 += __shfl_xor(ps0, 32, 64);
        ps1 += __shfl_xor(ps1, 16, 64); ps1 += __shfl_xor(ps1, 32, 64);
        ps2 += __shfl_xor(ps2, 16, 64); ps2 += __shfl_xor(ps2, 32, 64);
        ps3 += __shfl_xor(ps3, 16, 64); ps3 += __shfl_xor(ps3, 32, 64);
        if (q == 0) {
            red[w * 64 + l15]      = ps0;
            red[w * 64 + 16 + l15] = ps1;
            red[w * 64 + 32 + l15] = ps2;
            red[w * 64 + 48 + l15] = ps3;
        }
        __syncthreads();
        if (t < 64) {
            float s = red[t] + red[64 + t] + red[128 + t] + red[192 + t];
            atomicAdd(&pool[t], s);
        }
    }
}

__global__ __launch_bounds__(64) void final_kernel(const float* __restrict__ pool, const float* __restrict__ Wfc,
                                                   const float* __restrict__ bfc, float* __restrict__ out, int N) {
    int t = threadIdx.x;
    if (t < 24) {
        float inv = 1.0f / (float)N;
        float s = bfc[t];
        for (int c = 0; c < 64; ++c) s += pool[c] * inv * Wfc[c * 24 + t];
        out[t] = tanhf(s);
    }
}

extern "C" void kernel_launch(void* const* d_in, const int* in_sizes, int n_in,
                              void* d_out, int out_size, void* d_ws, size_t ws_size,
                              hipStream_t stream) {
    const float* x   = (const float*)d_in[0];
    const int*   ei  = (const int*)d_in[1];     // (2,E): row0 = src, row1 = dst
    // d_in[2] = batch (all zeros) -- unused
    const float* W1  = (const float*)d_in[3];
    const float* b1  = (const float*)d_in[4];
    const float* W2  = (const float*)d_in[5];
    const float* b2  = (const float*)d_in[6];
    const float* W3  = (const float*)d_in[7];
    const float* b3  = (const float*)d_in[8];
    const float* Wfc = (const float*)d_in[9];
    const float* bfc = (const float*)d_in[10];
    float* out = (float*)d_out;

    const int N = in_sizes[2];          // batch length = num nodes
    const int E = in_sizes[1] / 2;

    size_t off = 0;
    auto take = [&](size_t bytes) -> char* {
        char* p = (char*)d_ws + off;
        off = ALIGN256(off + bytes);
        return p;
    };
    int*    cnt   = (int*)   take((size_t)N * 4);
    float*  dinv  = (float*) take((size_t)N * 4);
    int2*   od    = (int2*)  take((size_t)N * 8);
    int*    cur   = (int*)   take((size_t)N * 4);
    int*    bsum  = (int*)   take(512 * 4);
    int*    bbase = (int*)   take(512 * 4);
    float*  pool  = (float*) take(64 * 4);
    int*    csr   = (int*)   take((size_t)E * 4);
    float4* xs    = (float4*)take((size_t)N * 16);
    __half* h16a  = (__half*)take((size_t)N * 64 * 2);
    __half* h16b  = (__half*)take((size_t)N * 64 * 2);
    (void)ws_size; (void)n_in; (void)out_size;

    const int NB = (N + 1023) / 1024;   // <= 512 for N <= 512k

    hipMemsetAsync(cnt, 0, (size_t)N * 4, stream);
    hipMemsetAsync(pool, 0, 64 * 4, stream);

    deg_kernel  <<<(E + 255) / 256, 256, 0, stream>>>(ei + E, cnt, E);
    dinvx_kernel<<<(N + 255) / 256, 256, 0, stream>>>(cnt, x, dinv, xs, N);
    scan1_kernel<<<NB, 256, 0, stream>>>(cnt, bsum, N);
    scan2_kernel<<<1, 512, 0, stream>>>(bsum, bbase, NB);
    scan3_kernel<<<NB, 256, 0, stream>>>(cnt, bbase, od, cur, N);
    fill_kernel <<<(E + 255) / 256, 256, 0, stream>>>(ei, cur, csr, E);

    // layer 1 (fused gather + 3->64 matmul), hs1 = dinv.*relu((S@x)@W1+b1)
    layer1_kernel<<<2048, 256, 0, stream>>>(xs, dinv, od, csr, W1, b1, h16a, N);

    const int ngroups = (N + 15) / 16;
    const int LB = (ngroups + 3) / 4;   // 1 group per wave

    // layer 2 (fused aggregate + MFMA matmul), hs2 = dinv.*relu((S@h1)@W2+b2)
    layer_kernel<0><<<LB, 256, 0, stream>>>(h16a, dinv, od, csr, W2, b2, h16b, nullptr, N);

    // layer 3 fused with mean-pool accumulation
    layer_kernel<1><<<LB, 256, 0, stream>>>(h16b, dinv, od, csr, W3, b3, nullptr, pool, N);

    final_kernel<<<1, 64, 0, stream>>>(pool, Wfc, bfc, out, N);
}

// Round 7
// 445.811 us; speedup vs baseline: 1.6087x; 1.6087x over previous
//
#include <hip/hip_runtime.h>
#include <hip/hip_bf16.h>
#include <hip/hip_fp16.h>

// CircuitGNN: 3-layer GCN (N=500k, E=1M, H=64) + mean pool + tanh FC head.
// v7: branch-free batched gather in layer_kernel:
//     - sentinel zero row at hin[N]: every load unconditional, address chosen
//       by SALU select (i < dg[m] ? csr idx : N). 16 loads -> 1 wait -> 16 adds.
//       (v6 put load+use inside per-m predicated regions -> serial vmcnt(0)
//        per load -> 237us. NEVER put a gather load and its use in the same
//        uniform branch region.)
//     - ~4 groups/wave (LB=2048): W-frag setup amortized, residency filled.
//     - layer1 split back to thread-per-node agg1 (64 independent lane chains
//       = natural MLP) + streaming mm1.
// v5 core kept: per-wave LDS A-tile + 8x mfma_f32_16x16x32_f16 vs
//     register-stationary W frags; h stored fp16 prescaled by dinv (L3-resident).
// History: v2 swizzled-LDS full-unroll spilled (VGPR 256) -- avoid.
//          v3/v4 readlane matmul: VALU-issue-bound (128 insts/node).
// Storage fp16; compute fp32 (MFMA f16-in/f32-acc).

#define ALIGN256(x) (((x) + 255) & ~(size_t)255)

typedef _Float16 half8 __attribute__((ext_vector_type(8)));
typedef float f32x4 __attribute__((ext_vector_type(4)));

__device__ __forceinline__ float rl(float v, int lane) {
    return __builtin_bit_cast(float, __builtin_amdgcn_readlane(__builtin_bit_cast(int, v), lane));
}

__global__ __launch_bounds__(256) void deg_kernel(const int* __restrict__ dst, int* __restrict__ cnt, int E) {
    int e = blockIdx.x * 256 + threadIdx.x;
    if (e < E) atomicAdd(&cnt[dst[e]], 1);
}

// dinv + prescaled xs (xs = dinv * x, padded to float4)
__global__ __launch_bounds__(256) void dinvx_kernel(const int* __restrict__ cnt, const float* __restrict__ x,
                                                    float* __restrict__ dinv, float4* __restrict__ xs, int N) {
    int i = blockIdx.x * 256 + threadIdx.x;
    if (i < N) {
        float d = rsqrtf((float)(cnt[i] + 1));   // +1 = self loop
        dinv[i] = d;
        xs[i] = make_float4(d * x[(size_t)i * 3 + 0], d * x[(size_t)i * 3 + 1],
                            d * x[(size_t)i * 3 + 2], 0.f);
    }
}

// ---- 2-level exclusive scan over cnt[N] ----
__global__ __launch_bounds__(256) void scan1_kernel(const int* __restrict__ cnt, int* __restrict__ bsum, int N) {
    __shared__ int s[256];
    int t = threadIdx.x, b = blockIdx.x;
    int i0 = b * 1024 + t * 4;
    int v = 0;
    if (i0 + 3 < N) { int4 q = *(const int4*)&cnt[i0]; v = q.x + q.y + q.z + q.w; }
    else { for (int k = 0; k < 4; ++k) if (i0 + k < N) v += cnt[i0 + k]; }
    s[t] = v; __syncthreads();
    for (int o = 128; o > 0; o >>= 1) { if (t < o) s[t] += s[t + o]; __syncthreads(); }
    if (t == 0) bsum[b] = s[0];
}

__global__ __launch_bounds__(512) void scan2_kernel(const int* __restrict__ bsum, int* __restrict__ bbase, int nb) {
    __shared__ int s[512];
    int t = threadIdx.x;
    int v = (t < nb) ? bsum[t] : 0;
    s[t] = v; __syncthreads();
    for (int off = 1; off < 512; off <<= 1) {
        int u = 0; if (t >= off) u = s[t - off];
        __syncthreads(); s[t] += u; __syncthreads();
    }
    if (t < nb) bbase[t] = s[t] - v;   // exclusive
}

// writes od[j] = (offset, deg) and cur[j] = offset
__global__ __launch_bounds__(256) void scan3_kernel(const int* __restrict__ cnt, const int* __restrict__ bbase,
                                                    int2* __restrict__ od, int* __restrict__ cur, int N) {
    __shared__ int s[256];
    int t = threadIdx.x, b = blockIdx.x;
    int i0 = b * 1024 + t * 4;
    int v0 = 0, v1 = 0, v2 = 0, v3 = 0;
    if (i0 + 3 < N) { int4 q = *(const int4*)&cnt[i0]; v0 = q.x; v1 = q.y; v2 = q.z; v3 = q.w; }
    else {
        if (i0 < N) v0 = cnt[i0];
        if (i0 + 1 < N) v1 = cnt[i0 + 1];
        if (i0 + 2 < N) v2 = cnt[i0 + 2];
        if (i0 + 3 < N) v3 = cnt[i0 + 3];
    }
    int ts = v0 + v1 + v2 + v3;
    s[t] = ts; __syncthreads();
    for (int off = 1; off < 256; off <<= 1) {
        int u = 0; if (t >= off) u = s[t - off];
        __syncthreads(); s[t] += u; __syncthreads();
    }
    int ex = s[t] - ts + bbase[b];
    int o0 = ex, o1 = ex + v0, o2 = o1 + v1, o3 = o2 + v2;
    if (i0     < N) { od[i0]     = make_int2(o0, v0); cur[i0]     = o0; }
    if (i0 + 1 < N) { od[i0 + 1] = make_int2(o1, v1); cur[i0 + 1] = o1; }
    if (i0 + 2 < N) { od[i0 + 2] = make_int2(o2, v2); cur[i0 + 2] = o2; }
    if (i0 + 3 < N) { od[i0 + 3] = make_int2(o3, v3); cur[i0 + 3] = o3; }
}

__global__ __launch_bounds__(256) void fill_kernel(const int* __restrict__ ei, int* __restrict__ cur,
                                                   int* __restrict__ csr, int E) {
    int e = blockIdx.x * 256 + threadIdx.x;
    if (e < E) {
        int s = ei[e], d = ei[E + e];
        int p = atomicAdd(&cur[d], 1);
        csr[p] = s;
    }
}

// ---- layer 1 aggregate (thread per node, xs prescaled): a1 = dj*(xs_j + sum xs_s) ----
__global__ __launch_bounds__(256) void agg1_kernel(const float4* __restrict__ xs, const float* __restrict__ dinv,
                                                   const int2* __restrict__ od, const int* __restrict__ csr,
                                                   float4* __restrict__ a1, int N) {
    int j = blockIdx.x * 256 + threadIdx.x;
    if (j >= N) return;
    float4 s = xs[j];
    int2 o = od[j];
    for (int i = 0; i < o.y; ++i) {
        float4 q = xs[csr[o.x + i]];
        s.x += q.x; s.y += q.y; s.z += q.z;
    }
    float dj = dinv[j];
    a1[j] = make_float4(dj * s.x, dj * s.y, dj * s.z, 0.f);
}

// ---- layer 1 matmul 3->64, wave grid-stride, writes prescaled fp16 ----
__global__ __launch_bounds__(256) void mm1_kernel(const float4* __restrict__ a1, const float* __restrict__ dinv,
                                                  const float* __restrict__ W1, const float* __restrict__ b1,
                                                  __half* __restrict__ hout, int N) {
    const int l = threadIdx.x & 63;
    const int wave = blockIdx.x * 4 + (threadIdx.x >> 6);
    const int stride = gridDim.x * 4;
    const float w0 = W1[l], w1 = W1[64 + l], w2 = W1[128 + l], bl = b1[l];
    for (int j = wave; j < N; j += stride) {
        float4 a = a1[j];
        float dj = dinv[j];
        float v = fmaf(a.x, w0, fmaf(a.y, w1, fmaf(a.z, w2, bl)));
        hout[(size_t)j * 64 + l] = __float2half(dj * fmaxf(v, 0.f));
    }
}

// ---- fused GCN layer v7: wave = 16 nodes/group, ~4 groups/wave.
//      Branch-free gather: sentinel zero row at hin[N]; per i-step 16
//      unconditional loads (SALU-selected addresses) -> 1 wait -> 16 adds.
//      Then LDS A-tile + 8x mfma_f32_16x16x32_f16 vs register W frags.
//      POOL=1 accumulates mean-pool numerator in registers. ----
template <int POOL>
__global__ __launch_bounds__(256) void layer_kernel(const __half* __restrict__ hin, const float* __restrict__ dinv,
                                                    const int2* __restrict__ od, const int* __restrict__ csr,
                                                    const float* __restrict__ W, const float* __restrict__ bias,
                                                    __half* __restrict__ hout, float* __restrict__ pool, int N) {
    const int t = threadIdx.x;
    const int l = t & 63;
    const int w = t >> 6;
    const int l15 = l & 15, q = l >> 4;

    __shared__ _Float16 aS[4][16 * 136 + 8];   // per-wave slice, row stride 136 (272 B)
    __shared__ float red[256];
    _Float16* as = aS[w];

    // B fragments of W (fp32 global -> f16 regs): lane holds
    // B[k = kt*32 + q*8 + j][col = ct*16 + l15], j=0..7. One-time, L2-hot.
    half8 bfr[4][2];
    #pragma unroll
    for (int ct = 0; ct < 4; ++ct)
        #pragma unroll
        for (int kt = 0; kt < 2; ++kt) {
            half8 b;
            #pragma unroll
            for (int j = 0; j < 8; ++j)
                b[j] = (_Float16)W[(kt * 32 + q * 8 + j) * 64 + ct * 16 + l15];
            bfr[ct][kt] = b;
        }
    float bb[4];
    #pragma unroll
    for (int ct = 0; ct < 4; ++ct) bb[ct] = bias[ct * 16 + l15];

    float ps0 = 0.f, ps1 = 0.f, ps2 = 0.f, ps3 = 0.f;

    const int ngroups = (N + 15) >> 4;
    const int gstride = gridDim.x * 4;
    for (int g = blockIdx.x * 4 + w; g < ngroups; g += gstride) {
        const int j0 = g << 4;
        // od/dinv for the group's 16 nodes (lanes 0..15, coalesced)
        float djv = 0.f; int oxv = 0, oyv = 0;
        if (l < 16 && j0 + l < N) {
            int2 o = od[j0 + l];
            oxv = o.x; oyv = o.y;
            djv = dinv[j0 + l];
        }
        // hoist offsets/degrees to SGPRs
        int offr[16], dg[16];
        const int mlast = min(15, N - 1 - j0);
        const int base = __builtin_amdgcn_readlane(oxv, 0);
        #pragma unroll
        for (int m = 0; m < 16; ++m) {
            offr[m] = __builtin_amdgcn_readlane(oxv, m) - base;
            dg[m]   = __builtin_amdgcn_readlane(oyv, m);
        }
        const int span = offr[mlast] + dg[mlast];

        // prefetch whole group's neighbor indices (contiguous in CSR)
        int nb0 = 0, nb1 = 0;
        if (l < span)      nb0 = csr[base + l];
        if (64 + l < span) nb1 = csr[base + 64 + l];

        // self rows: unconditional via sentinel row N
        float acc[16];
        #pragma unroll
        for (int m = 0; m < 16; ++m) {
            int j = (j0 + m < N) ? (j0 + m) : N;
            acc[m] = __half2float(hin[(size_t)j * 64 + l]);
        }

        if (span <= 128) {
            int dmax = 0;
            #pragma unroll
            for (int m = 0; m < 16; ++m) dmax = max(dmax, dg[m]);
            for (int i = 0; i < dmax; ++i) {
                float gval[16];
                #pragma unroll
                for (int m = 0; m < 16; ++m) {
                    bool ok = (i < dg[m]);                  // wave-uniform
                    int idc = ok ? (offr[m] + i) : 0;       // clamped for readlane
                    int s = (idc < 64) ? __builtin_amdgcn_readlane(nb0, idc)
                                       : __builtin_amdgcn_readlane(nb1, idc - 64);
                    s = ok ? s : N;                         // sentinel zero row
                    gval[m] = __half2float(hin[(size_t)s * 64 + l]);
                }
                #pragma unroll
                for (int m = 0; m < 16; ++m) acc[m] += gval[m];
            }
        } else {
            // rare fallback: per-node serial gathers
            #pragma unroll 1
            for (int m = 0; m < 16; ++m) {
                const int* cp = csr + base + offr[m];
                int dgm = dg[m];
                for (int i = 0; i < dgm; ++i)
                    acc[m] += __half2float(hin[(size_t)cp[i] * 64 + l]);
            }
        }

        // scale + stage to LDS (A-frag layout)
        #pragma unroll
        for (int m = 0; m < 16; ++m)
            as[m * 136 + l] = (_Float16)(rl(djv, m) * acc[m]);
        __asm__ volatile("s_waitcnt lgkmcnt(0)" ::: "memory");

        // Phase B: A-frags (A[m=l15][k=q*8+j] per ktile) + 8 MFMA
        half8 af0 = *(const half8*)&as[l15 * 136 + q * 8];
        half8 af1 = *(const half8*)&as[l15 * 136 + 32 + q * 8];
        f32x4 c0 = {0.f, 0.f, 0.f, 0.f}, c1 = c0, c2 = c0, c3 = c0;
        c0 = __builtin_amdgcn_mfma_f32_16x16x32_f16(af0, bfr[0][0], c0, 0, 0, 0);
        c1 = __builtin_amdgcn_mfma_f32_16x16x32_f16(af0, bfr[1][0], c1, 0, 0, 0);
        c2 = __builtin_amdgcn_mfma_f32_16x16x32_f16(af0, bfr[2][0], c2, 0, 0, 0);
        c3 = __builtin_amdgcn_mfma_f32_16x16x32_f16(af0, bfr[3][0], c3, 0, 0, 0);
        c0 = __builtin_amdgcn_mfma_f32_16x16x32_f16(af1, bfr[0][1], c0, 0, 0, 0);
        c1 = __builtin_amdgcn_mfma_f32_16x16x32_f16(af1, bfr[1][1], c1, 0, 0, 0);
        c2 = __builtin_amdgcn_mfma_f32_16x16x32_f16(af1, bfr[2][1], c2, 0, 0, 0);
        c3 = __builtin_amdgcn_mfma_f32_16x16x32_f16(af1, bfr[3][1], c3, 0, 0, 0);

        // Epilogue: C[row = q*4+r][col = ct*16+l15]
        if (POOL) {
            #pragma unroll
            for (int r = 0; r < 4; ++r) {
                int gj = j0 + q * 4 + r;
                if (gj < N) {
                    ps0 += fmaxf(c0[r] + bb[0], 0.f);
                    ps1 += fmaxf(c1[r] + bb[1], 0.f);
                    ps2 += fmaxf(c2[r] + bb[2], 0.f);
                    ps3 += fmaxf(c3[r] + bb[3], 0.f);
                }
            }
        } else {
            #pragma unroll
            for (int r = 0; r < 4; ++r) {
                int row = q * 4 + r;
                int gj = j0 + row;
                float djr = __shfl(djv, row, 64);
                if (gj < N) {
                    size_t bse = (size_t)gj * 64 + l15;
                    hout[bse]      = __float2half(djr * fmaxf(c0[r] + bb[0], 0.f));
                    hout[bse + 16] = __float2half(djr * fmaxf(c1[r] + bb[1], 0.f));
                    hout[bse + 32] = __float2half(djr * fmaxf(c2[r] + bb[2], 0.f));
                    hout[bse + 48] = __float2half(djr * fmaxf(c3[r] + bb[3], 0.f));
                }
            }
        }
    }

    if (POOL) {
        ps0 += __shfl_xor(ps0, 16, 64); ps0 += __shfl_xor(ps0, 32, 64);
        ps1 += __shfl_xor(ps1, 16, 64); ps1 += __shfl_xor(ps1, 32, 64);
        ps2 += __shfl_xor(ps2, 16, 64); ps2 += __shfl_xor(ps2, 32, 64);
        ps3 += __shfl_xor(ps3, 16, 64); ps3 += __shfl_xor(ps3, 32, 64);
        if (q == 0) {
            red[w * 64 + l15]      = ps0;
            red[w * 64 + 16 + l15] = ps1;
            red[w * 64 + 32 + l15] = ps2;
            red[w * 64 + 48 + l15] = ps3;
        }
        __syncthreads();
        if (t < 64) {
            float s = red[t] + red[64 + t] + red[128 + t] + red[192 + t];
            atomicAdd(&pool[t], s);
        }
    }
}

__global__ __launch_bounds__(64) void final_kernel(const float* __restrict__ pool, const float* __restrict__ Wfc,
                                                   const float* __restrict__ bfc, float* __restrict__ out, int N) {
    int t = threadIdx.x;
    if (t < 24) {
        float inv = 1.0f / (float)N;
        float s = bfc[t];
        for (int c = 0; c < 64; ++c) s += pool[c] * inv * Wfc[c * 24 + t];
        out[t] = tanhf(s);
    }
}

extern "C" void kernel_launch(void* const* d_in, const int* in_sizes, int n_in,
                              void* d_out, int out_size, void* d_ws, size_t ws_size,
                              hipStream_t stream) {
    const float* x   = (const float*)d_in[0];
    const int*   ei  = (const int*)d_in[1];     // (2,E): row0 = src, row1 = dst
    // d_in[2] = batch (all zeros) -- unused
    const float* W1  = (const float*)d_in[3];
    const float* b1  = (const float*)d_in[4];
    const float* W2  = (const float*)d_in[5];
    const float* b2  = (const float*)d_in[6];
    const float* W3  = (const float*)d_in[7];
    const float* b3  = (const float*)d_in[8];
    const float* Wfc = (const float*)d_in[9];
    const float* bfc = (const float*)d_in[10];
    float* out = (float*)d_out;

    const int N = in_sizes[2];          // batch length = num nodes
    const int E = in_sizes[1] / 2;

    size_t off = 0;
    auto take = [&](size_t bytes) -> char* {
        char* p = (char*)d_ws + off;
        off = ALIGN256(off + bytes);
        return p;
    };
    int*    cnt   = (int*)   take((size_t)N * 4);
    float*  dinv  = (float*) take((size_t)N * 4);
    int2*   od    = (int2*)  take((size_t)N * 8);
    int*    cur   = (int*)   take((size_t)N * 4);
    int*    bsum  = (int*)   take(512 * 4);
    int*    bbase = (int*)   take(512 * 4);
    float*  pool  = (float*) take(64 * 4);
    int*    csr   = (int*)   take((size_t)E * 4);
    float4* xs    = (float4*)take((size_t)N * 16);
    float4* a1    = (float4*)take((size_t)N * 16);
    __half* h16a  = (__half*)take((size_t)(N + 1) * 64 * 2);   // +1 sentinel zero row
    __half* h16b  = (__half*)take((size_t)(N + 1) * 64 * 2);
    (void)ws_size; (void)n_in; (void)out_size;

    const int NB = (N + 1023) / 1024;   // <= 512 for N <= 512k

    hipMemsetAsync(cnt, 0, (size_t)N * 4, stream);
    hipMemsetAsync(pool, 0, 64 * 4, stream);
    hipMemsetAsync(h16a + (size_t)N * 64, 0, 128, stream);     // sentinel rows
    hipMemsetAsync(h16b + (size_t)N * 64, 0, 128, stream);

    deg_kernel  <<<(E + 255) / 256, 256, 0, stream>>>(ei + E, cnt, E);
    dinvx_kernel<<<(N + 255) / 256, 256, 0, stream>>>(cnt, x, dinv, xs, N);
    scan1_kernel<<<NB, 256, 0, stream>>>(cnt, bsum, N);
    scan2_kernel<<<1, 512, 0, stream>>>(bsum, bbase, NB);
    scan3_kernel<<<NB, 256, 0, stream>>>(cnt, bbase, od, cur, N);
    fill_kernel <<<(E + 255) / 256, 256, 0, stream>>>(ei, cur, csr, E);

    // layer 1: a1 = S@xs (thread-per-node), hs1 = dinv.*relu(a1@W1+b1)
    agg1_kernel<<<(N + 255) / 256, 256, 0, stream>>>(xs, dinv, od, csr, a1, N);
    mm1_kernel <<<1280, 256, 0, stream>>>(a1, dinv, W1, b1, h16a, N);

    const int LB = 2048;    // 8192 waves, ~3.8 groups/wave

    // layer 2 (fused aggregate + MFMA matmul), hs2 = dinv.*relu((S@h1)@W2+b2)
    layer_kernel<0><<<LB, 256, 0, stream>>>(h16a, dinv, od, csr, W2, b2, h16b, nullptr, N);

    // layer 3 fused with mean-pool accumulation
    layer_kernel<1><<<LB, 256, 0, stream>>>(h16b, dinv, od, csr, W3, b3, nullptr, pool, N);

    final_kernel<<<1, 64, 0, stream>>>(pool, Wfc, bfc, out, N);
}